// Round 5
// baseline (570.814 us; speedup 1.0000x reference)
//
#include <hip/hip_runtime.h>
#include <hip/hip_bf16.h>
#include <stdint.h>

typedef unsigned short u16;
typedef unsigned int u32;
typedef __bf16 bf16x8 __attribute__((ext_vector_type(8)));
typedef float f32x4 __attribute__((ext_vector_type(4)));
typedef u16 u16x4 __attribute__((ext_vector_type(4)));
typedef u16 u16x8 __attribute__((ext_vector_type(8)));

typedef const __attribute__((address_space(1))) void* gas_ptr;
typedef __attribute__((address_space(3))) void* las_ptr;

#define M_DIM 8192
#define K_DIM 4096
#define N_DIM 4096

__device__ __forceinline__ u16 f32_to_bf16_rne(float f) {
    u32 u = __float_as_uint(f);
    u += 0x7FFFu + ((u >> 16) & 1u);
    return (u16)(u >> 16);
}

// ---- 1) fused: xb fp32->bf16 cast (blocks 0..4095) + max|W| reduction (blocks 4096..5119).
#define CAST_BLOCKS 4096
#define MAX_BLOCKS 1024
__global__ void cast_maxabs_kernel(const float* __restrict__ x, u16* __restrict__ y,
                                   const float* __restrict__ W, u32* __restrict__ out) {
    const int bid = blockIdx.x;
    if (bid < CAST_BLOCKS) {
        const int n4 = (M_DIM * K_DIM) / 4;
        int idx = bid * 256 + threadIdx.x;
        const int stride = CAST_BLOCKS * 256;
        const float4* x4 = (const float4*)x;
        u16x4* y4 = (u16x4*)y;
        for (int i = idx; i < n4; i += stride) {
            float4 v = x4[i];
            u16x4 o;
            o.x = f32_to_bf16_rne(v.x);
            o.y = f32_to_bf16_rne(v.y);
            o.z = f32_to_bf16_rne(v.z);
            o.w = f32_to_bf16_rne(v.w);
            y4[i] = o;
        }
    } else {
        const int n4 = (K_DIM * N_DIM) / 4;
        int idx = (bid - CAST_BLOCKS) * 256 + threadIdx.x;
        const int stride = MAX_BLOCKS * 256;
        const float4* W4 = (const float4*)W;
        float m = 0.0f;
        for (int i = idx; i < n4; i += stride) {
            float4 v = W4[i];
            m = fmaxf(m, fmaxf(fmaxf(fabsf(v.x), fabsf(v.y)), fmaxf(fabsf(v.z), fabsf(v.w))));
        }
#pragma unroll
        for (int off = 32; off > 0; off >>= 1)
            m = fmaxf(m, __shfl_down(m, off));
        if ((threadIdx.x & 63) == 0)
            atomicMax(out, __float_as_uint(m));
    }
}

// ---- 2) quantize W (K x N, fp32) -> bf16 W^T in WAVE-FRAGMENT-TILED layout.
// Element (n,k) -> decompose n = (ntile<<8)+(wn<<6)+(nh<<5)+(j<<4)+l15, k = (T<<6)+(ks<<5)+(quad<<3)+e.
// u16 offset = ((n>>6)*64 + T)*4096 + ((nh*2+j)*2+ks)*512 + (quad*16+l15)*8 + e.
// This makes each GEMM wave's per-K-tile B fragment one contiguous 8KB run (8 x 1KB chunks,
// chunk c = (nh*2+j)*2+ks, lane slot = quad*16+l15) -> perfectly coalesced register loads.
// Values identical to the plain W^T (same quantize math) -> GEMM output bitwise unchanged.
__device__ __forceinline__ u16 quantize_bf16(float v, float s_inv) {
    float q = rintf(v * s_inv);  // rintf = round-half-even (matches jnp.round)
    q = fminf(fmaxf(q, -127.0f), 127.0f);
    return (u16)(__float_as_uint(q) >> 16);  // truncation exact for small ints
}

__global__ void quant_transpose_kernel(const float* __restrict__ W, u16* __restrict__ Wt,
                                       const u32* __restrict__ mb) {
    __shared__ u16 tile[64][73];  // [k_local][n_local], padded row
    const float s_inv = 128.0f / __uint_as_float(*mb);  // 1/s_w, s_w = 2*max/256 = max/128
    const int n0 = blockIdx.x * 64;
    const int k0 = blockIdx.y * 64;
    const int t = threadIdx.x;  // 256 threads

    // load: 64 k-rows x 64 n; thread t handles row (p*16 + t/16), n-offset (t%16)*4
    const int lr = t >> 4;
    const int lc = (t & 15) * 4;
#pragma unroll
    for (int p = 0; p < 4; ++p) {
        const int k = k0 + p * 16 + lr;
        const float4 v = *(const float4*)&W[(size_t)k * N_DIM + n0 + lc];
        u16* d = &tile[p * 16 + lr][lc];
        d[0] = quantize_bf16(v.x, s_inv);
        d[1] = quantize_bf16(v.y, s_inv);
        d[2] = quantize_bf16(v.z, s_inv);
        d[3] = quantize_bf16(v.w, s_inv);
    }
    __syncthreads();

    // store to tiled layout: thread t -> n = p*32 + sr (p=nh), k-cols sc..sc+7
    const int sr = t >> 3;           // 0..31
    const int sc = (t & 7) * 8;      // 0..56
    const int j = (sr >> 4) & 1;
    const int l15 = sr & 15;
    const int ks = sc >> 5;
    const int quad = (sc >> 3) & 3;
    // block-uniform base: (n>>6)=blockIdx.x, T=blockIdx.y
    const size_t base = ((size_t)blockIdx.x * 64 + blockIdx.y) * 4096;
#pragma unroll
    for (int p = 0; p < 2; ++p) {
        u16x8 o;
#pragma unroll
        for (int e = 0; e < 8; ++e) o[e] = tile[sc + e][p * 32 + sr];
        const size_t off = base + (size_t)(((p * 2 + j) * 2 + ks) * 512 + (quad * 16 + l15) * 8);
        *(u16x8*)&Wt[off] = o;
    }
}

// ---- 3) GEMM: out[M][N] = s_w * (A[M][K] @ B^T) + bias
// 256x256 tile, BK=64, 8 waves (2M x 4N). B comes STRAIGHT FROM GLOBAL to registers
// (tiled layout above): LDS holds only A (2 x 32KB double-buffer) -> LDS pipe (~1792cy/Ktile)
// now UNDER the MFMA floor (~2484cy); 1 barrier per K-tile; counted vmcnt never drains to 0.
// NH-major phases: cluster NH=0 (cols 0..31) then NH=1, B halves prefetched with zero extra
// VGPRs via in-order WAR renaming (b_lo(T+1) loads issue after b_lo(T)'s last MFMA).
// A-side staging + XOR swizzle unchanged (bank conflicts measured 0).

#define BAR() __builtin_amdgcn_s_barrier()
#define SCB() __builtin_amdgcn_sched_barrier(0)
#define LGKM0()                                            \
    do {                                                   \
        asm volatile("s_waitcnt lgkmcnt(0)" ::: "memory"); \
        __builtin_amdgcn_sched_barrier(0);                 \
    } while (0)
#define VMC(N)                                                  \
    do {                                                        \
        asm volatile("s_waitcnt vmcnt(" #N ")" ::: "memory");   \
        __builtin_amdgcn_sched_barrier(0);                      \
    } while (0)
#define PRIO1() __builtin_amdgcn_s_setprio(1)
#define PRIO0() __builtin_amdgcn_s_setprio(0)

// ds_read full A panel (128 rows x 64k per wave): a[mi][ks], rows wm*128 + mi*16 + l15
#define DS_ALL(BUFOFF)                                          \
    do {                                                        \
        _Pragma("unroll") for (int mi_ = 0; mi_ < 8; ++mi_) {   \
            const char* p_ = asb + (BUFOFF) + mi_ * 2048;       \
            a[mi_][0] = *(const bf16x8*)(p_ + ck0);             \
            a[mi_][1] = *(const bf16x8*)(p_ + ck1);             \
        }                                                       \
    } while (0)

// load B chunk c of k-tile T into b[c>>1][c&1] (1KB per instr per wave, contiguous)
#define LOADB(T, C) \
    b[(C) >> 1][(C)&1] = *(const bf16x8*)(Bw + (size_t)(T)*4096 + (C)*512 + lane * 8)

// 32 MFMAs: one NH half (cols NH*32..+32) x full K=64. Per-element k-order ks0->ks1 (bitwise
// identical accumulation to previous rounds).
#define CL(NH)                                                                                  \
    do {                                                                                        \
        _Pragma("unroll") for (int mi_ = 0; mi_ < 8; ++mi_) {                                   \
            _Pragma("unroll") for (int j_ = 0; j_ < 2; ++j_) {                                  \
                f32x4& c_ = acc[mi_][(NH)*2 + j_];                                              \
                c_ = __builtin_amdgcn_mfma_f32_16x16x32_bf16(a[mi_][0], b[(NH)*2 + j_][0], c_,  \
                                                             0, 0, 0);                          \
                c_ = __builtin_amdgcn_mfma_f32_16x16x32_bf16(a[mi_][1], b[(NH)*2 + j_][1], c_,  \
                                                             0, 0, 0);                          \
            }                                                                                   \
        }                                                                                       \
    } while (0)

// stage full A k-tile T (256 rows x 64k) into LDS at BUFOFF: 4 gl_lds per wave,
// rows wave*8 + {0,64,128,192}
#define STAGE_A4(BUFOFF, T)                                                                    \
    do {                                                                                       \
        _Pragma("unroll") for (int h_ = 0; h_ < 4; ++h_) {                                     \
            const int r0_ = wave_u * 8 + h_ * 64;                                              \
            __builtin_amdgcn_global_load_lds((gas_ptr)(Ag + (size_t)r0_ * K_DIM + (T)*64),     \
                                             (las_ptr)(lds_raw + (BUFOFF) + r0_ * 128), 16, 0, \
                                             0);                                               \
        }                                                                                      \
    } while (0)

// One K-tile, ONE barrier. Read A from BUFOFF, stage tile TS=T+1 into OBUFOFF.
// vmcnt FIFO per wave (steady state): entering tile: [b_lo(T)(4)].
//  [1] b_hi(T) x4   [2] stageA(T+1) x4   [3] dsA + lgkm0
//  [4] VMC(8): retires b_lo(T)           [5] CL(0)
//  [6] b_lo(T+1) x4 [7] VMC(8): retires b_hi(T)   [8] CL(1)
//  [9] VMC(4): retires stageA(T+1)  [10] BAR  -> leaves [b_lo(T+1)(4)] in flight.
#define KTILE(BUFOFF, OBUFOFF, T)     \
    do {                              \
        LOADB(T, 4);                  \
        LOADB(T, 5);                  \
        LOADB(T, 6);                  \
        LOADB(T, 7);                  \
        STAGE_A4(OBUFOFF, (T) + 1);   \
        DS_ALL(BUFOFF);               \
        LGKM0();                      \
        VMC(8);                       \
        PRIO1();                      \
        CL(0);                        \
        PRIO0();                      \
        LOADB((T) + 1, 0);            \
        LOADB((T) + 1, 1);            \
        LOADB((T) + 1, 2);            \
        LOADB((T) + 1, 3);            \
        VMC(8);                       \
        PRIO1();                      \
        CL(1);                        \
        PRIO0();                      \
        VMC(4);                       \
        BAR();                        \
    } while (0)

__global__ __launch_bounds__(512, 2) void gemm_kernel(const u16* __restrict__ A,
                                                      const u16* __restrict__ Btt,
                                                      const float* __restrict__ bias,
                                                      const u32* __restrict__ mb,
                                                      float* __restrict__ out) {
    extern __shared__ u16 lds_u16[];  // 64 KiB dynamic: A buf0 (32KB), A buf1 (32KB)
    char* lds_raw = (char*)lds_u16;

    const int tid = threadIdx.x;
    const int wave_u = __builtin_amdgcn_readfirstlane(tid >> 6);  // wave-uniform in SGPR
    const int lane = tid & 63;
    const int quad = lane >> 4;
    const int l15 = lane & 15;
    const int wm = wave_u >> 2;  // 0..1 : rows [wm*128, +128)
    const int wn = wave_u & 3;   // 0..3 : cols [wn*64, +64)

    // XCD-aware block swizzle (512 blocks, 8 XCDs, 64/XCD; then M-row-major within chunk)
    const int bswz = (blockIdx.x & 7) * 64 + (blockIdx.x >> 3);
    const int m0 = (bswz >> 4) * 256;  // 32 M-tiles
    const int n0 = (bswz & 15) * 256;  // 16 N-tiles

    // A staging lane map: lane l writes phys LDS chunk (row r0+(l>>3), chunk l&7);
    // source col chunk = (l&7) ^ (l>>3) (inverse of the read-side XOR; r0 multiple of 8)
    const int stg_row = lane >> 3;
    const int stg_col = ((lane & 7) ^ stg_row) * 8;  // u16 units
    const u16* Ag = A + (size_t)(m0 + stg_row) * K_DIM + stg_col;

    // B wave base in tiled layout: (n0>>6 + wn) * 64tiles * 4096 u16
    const u16* Bw = Btt + (size_t)((n0 >> 6) + wn) * 262144;

    // ds_read swizzled column offsets: (ks*64 + quad*16) ^ ((l15&7)<<4)
    const int xorv = (l15 & 7) << 4;
    const int ck0 = (quad * 16) ^ xorv;
    const int ck1 = (64 + quad * 16) ^ xorv;
    const char* asb = lds_raw + wm * 16384 + l15 * 128;  // buf0 base; buf1 = +32768

    bf16x8 a[8][2];
    bf16x8 b[4][2];
    f32x4 acc[8][4];
#pragma unroll
    for (int i = 0; i < 8; i++)
#pragma unroll
        for (int j = 0; j < 4; j++) acc[i][j] = (f32x4){0.f, 0.f, 0.f, 0.f};

    // ---- prologue: stage A(0) -> buf0; issue b_lo(0); stage retired, b_lo left in flight
    STAGE_A4(0, 0);
    LOADB(0, 0);
    LOADB(0, 1);
    LOADB(0, 2);
    LOADB(0, 3);
    VMC(4);
    BAR();

    // ---- main loop: tiles 0..61 (31 iters x 2), then peeled 62 + 63 (no OOB prefetch)
#pragma unroll 1
    for (int t = 0; t < 62; t += 2) {
        KTILE(0, 32768, t);
        KTILE(32768, 0, t + 1);
    }
    // tile 62 (buf0): normal — stages A(63), prefetches b_lo(63)
    KTILE(0, 32768, 62);
    // tile 63 (buf1): no staging, no b_lo(64). Entering: [b_lo(63)(4)] in flight.
    LOADB(63, 4);
    LOADB(63, 5);
    LOADB(63, 6);
    LOADB(63, 7);
    DS_ALL(32768);
    LGKM0();
    VMC(4);  // retires b_lo(63)
    PRIO1();
    CL(0);
    PRIO0();
    VMC(0);  // retires b_hi(63)
    PRIO1();
    CL(1);
    PRIO0();

    // ---- epilogue: C/D layout col = l15 (N), row = quad*4 + reg (M)  [m89/m91-verified]
    const float s_w = __uint_as_float(*mb) * (1.0f / 128.0f);
#pragma unroll
    for (int nj = 0; nj < 4; ++nj) {
        const int col = n0 + wn * 64 + nj * 16 + l15;
        const float bv = bias[col];
#pragma unroll
        for (int mi = 0; mi < 8; ++mi) {
            const int row = m0 + wm * 128 + mi * 16 + quad * 4;
            float* op = out + (size_t)row * N_DIM + col;
#pragma unroll
            for (int r = 0; r < 4; ++r) op[(size_t)r * N_DIM] = s_w * acc[mi][nj][r] + bv;
        }
    }
}

extern "C" void kernel_launch(void* const* d_in, const int* in_sizes, int n_in,
                              void* d_out, int out_size, void* d_ws, size_t ws_size,
                              hipStream_t stream) {
    const float* xb = (const float*)d_in[0];  // 8192 x 4096 fp32
    const float* W = (const float*)d_in[1];   // 4096 x 4096 fp32
    const float* b = (const float*)d_in[2];   // 4096 fp32
    float* out = (float*)d_out;               // 8192 x 4096 fp32

    // workspace layout: [0,4): maxabs bits | [256, 256+64M): xb bf16 | then W^T tiled bf16 (32M)
    u32* mb = (u32*)d_ws;
    u16* xb_bf = (u16*)((char*)d_ws + 256);
    u16* wqt = (u16*)((char*)d_ws + 256 + (size_t)M_DIM * K_DIM * 2);

    hipMemsetAsync(d_ws, 0, 4, stream);  // ws is re-poisoned 0xAA before every call
    cast_maxabs_kernel<<<CAST_BLOCKS + MAX_BLOCKS, 256, 0, stream>>>(xb, xb_bf, W, mb);
    quant_transpose_kernel<<<dim3(N_DIM / 64, K_DIM / 64), 256, 0, stream>>>(W, wqt, mb);
    gemm_kernel<<<dim3(512), dim3(512), 65536, stream>>>(xb_bf, wqt, b, mb, out);
}